// Round 1
// baseline (843.094 us; speedup 1.0000x reference)
//
#include <hip/hip_runtime.h>
#include <math.h>

#define NN 100000
#define NE 1600000
#define IN_F 16
#define OUT_F 64
#define PERIODS 12
#define FP (IN_F * PERIODS) /* 192 */
#define N_PHASE 4
#define SCAN_B 1024
#define N_CHUNKS ((NN + SCAN_B - 1) / SCAN_B) /* 98 */

// ---------------- prep: fused weights + softmax(attn) ----------------
// Az[f][j] = sum_k conv_z_w[f][k] * lin_z_w[k][j]   (only rows 0..63 of lin_z_w matter: H0==0)
// cz[j]    = sum_k conv_z_b[k]    * lin_z_w[k][j] + lin_z_b[j]
__global__ void k_prep(const float* __restrict__ attn,
                       const float* __restrict__ czw, const float* __restrict__ czb,
                       const float* __restrict__ chw, const float* __restrict__ chb,
                       const float* __restrict__ lzw, const float* __restrict__ lzb,
                       const float* __restrict__ lhw, const float* __restrict__ lhb,
                       float* __restrict__ Az, float* __restrict__ Ah,
                       float* __restrict__ cz, float* __restrict__ ch,
                       float* __restrict__ probs) {
  int t = threadIdx.x;          // 1024 threads
  int f = t >> 6, j = t & 63;   // f in [0,16), j in [0,64)
  float az = 0.f, ah = 0.f;
  for (int k = 0; k < 64; ++k) {
    az += czw[f * 64 + k] * lzw[k * 64 + j];
    ah += chw[f * 64 + k] * lhw[k * 64 + j];
  }
  Az[t] = az;
  Ah[t] = ah;
  if (t < 64) {
    float vz = lzb[t], vh = lhb[t];
    for (int k = 0; k < 64; ++k) {
      vz += czb[k] * lzw[k * 64 + t];
      vh += chb[k] * lhw[k * 64 + t];
    }
    cz[t] = vz;
    ch[t] = vh;
  }
  if (t == 0) {
    float m = -1e30f;
    for (int p = 0; p < PERIODS; ++p) m = fmaxf(m, attn[p]);
    float e[PERIODS], s = 0.f;
    for (int p = 0; p < PERIODS; ++p) { e[p] = __expf(attn[p] - m); s += e[p]; }
    for (int p = 0; p < PERIODS; ++p) probs[p] = e[p] / s;
  }
}

// ---------------- degree histogram ----------------
__global__ void k_hist(const int* __restrict__ dst, int* __restrict__ deg) {
  int e = blockIdx.x * blockDim.x + threadIdx.x;
  if (e < NE) atomicAdd(&deg[dst[e]], 1);
}

// ---------------- scan (3-kernel) ----------------
__global__ void k_scan_a(const int* __restrict__ deg, int* __restrict__ row_excl,
                         float* __restrict__ dinv, int* __restrict__ chunk_total) {
  __shared__ int s[SCAN_B];
  int t = threadIdx.x;
  int i = blockIdx.x * SCAN_B + t;
  int v = (i < NN) ? deg[i] : 0;
  s[t] = v;
  __syncthreads();
  for (int o = 1; o < SCAN_B; o <<= 1) {
    int add = (t >= o) ? s[t - o] : 0;
    __syncthreads();
    s[t] += add;
    __syncthreads();
  }
  if (i < NN) {
    row_excl[i] = s[t] - v;                 // chunk-local exclusive
    dinv[i] = rsqrtf((float)(v + 1));       // +1 self loop; deg>=1 always
  }
  if (t == SCAN_B - 1) chunk_total[blockIdx.x] = s[t];
}

__global__ void k_scan_b(const int* __restrict__ chunk_total, int* __restrict__ chunk_off) {
  __shared__ int s[128];
  int t = threadIdx.x; // 128
  int v = (t < N_CHUNKS) ? chunk_total[t] : 0;
  s[t] = v;
  __syncthreads();
  for (int o = 1; o < 128; o <<= 1) {
    int add = (t >= o) ? s[t - o] : 0;
    __syncthreads();
    s[t] += add;
    __syncthreads();
  }
  chunk_off[t] = s[t] - v;
}

__global__ void k_scan_c(int* __restrict__ row_excl, const int* __restrict__ chunk_off,
                         int* __restrict__ cursor) {
  int i = blockIdx.x * SCAN_B + threadIdx.x;
  if (i < NN) {
    int r = row_excl[i] + chunk_off[blockIdx.x];
    row_excl[i] = r;
    cursor[i] = r;
  }
}

// ---------------- CSR fill ----------------
__global__ void k_fill(const int* __restrict__ src, const int* __restrict__ dst,
                       int* __restrict__ cursor, int* __restrict__ csr_src) {
  int e = blockIdx.x * blockDim.x + threadIdx.x;
  if (e < NE) {
    int d = dst[e];
    int pos = atomicAdd(&cursor[d], 1);
    csr_src[pos] = src[e];
  }
}

// ---------------- fused gather + GRU-collapsed compute + head ----------------
__global__ __launch_bounds__(192) void k_main(
    const float* __restrict__ x, const int* __restrict__ csr_src,
    const int* __restrict__ row_start, const int* __restrict__ deg,
    const float* __restrict__ dinv,
    const float* __restrict__ Az, const float* __restrict__ Ah,
    const float* __restrict__ cz, const float* __restrict__ ch,
    const float* __restrict__ probs,
    const float* __restrict__ out_w, const float* __restrict__ out_b,
    float* __restrict__ out) {
  __shared__ float y[FP];
  __shared__ float hpart[192];
  int n = blockIdx.x;
  int t = threadIdx.x;

  // Phase A: gather y[n] = dinv[n] * ( sum_e dinv[src] x[src] + dinv[n] x[n] )
  float dn = dinv[n];
  float acc = dn * x[(size_t)n * FP + t];
  int base = row_start[n];
  int cnt = deg[n];
  for (int i = 0; i < cnt; ++i) {
    int s = csr_src[base + i];
    acc += dinv[s] * x[(size_t)s * FP + t];
  }
  y[t] = dn * acc;
  __syncthreads();

  // Phase B: wave w handles periods 4w..4w+3; lane j owns feature j
  int w = t >> 6, j = t & 63;
  float Azj[IN_F], Ahj[IN_F];
#pragma unroll
  for (int f = 0; f < IN_F; ++f) { Azj[f] = Az[f * 64 + j]; Ahj[f] = Ah[f * 64 + j]; }
  float bz = cz[j], bh = ch[j];
  float Hacc = 0.f;
#pragma unroll
  for (int pp = 0; pp < 4; ++pp) {
    int p = w * 4 + pp;
    float z = bz, h = bh;
#pragma unroll
    for (int f = 0; f < IN_F; ++f) {
      float yv = y[f * PERIODS + p];   // LDS broadcast (same addr all lanes)
      z = fmaf(yv, Azj[f], z);
      h = fmaf(yv, Ahj[f], h);
    }
    float Z = 1.f / (1.f + __expf(-z));
    float T = 1.f - 2.f / (__expf(2.f * h) + 1.f);  // tanh; saturates correctly at +/-inf
    Hacc += probs[p] * (1.f - Z) * T;
  }
  hpart[t] = Hacc;
  __syncthreads();

  // Phase C (wave 0): combine period-partials, relu, 64->4 head, softmax
  if (w == 0) {
    float h = hpart[j] + hpart[64 + j] + hpart[128 + j];
    h = fmaxf(h, 0.f);
    float l0 = h * out_w[j * 4 + 0];
    float l1 = h * out_w[j * 4 + 1];
    float l2 = h * out_w[j * 4 + 2];
    float l3 = h * out_w[j * 4 + 3];
#pragma unroll
    for (int o = 1; o < 64; o <<= 1) {
      l0 += __shfl_xor(l0, o, 64);
      l1 += __shfl_xor(l1, o, 64);
      l2 += __shfl_xor(l2, o, 64);
      l3 += __shfl_xor(l3, o, 64);
    }
    l0 += out_b[0]; l1 += out_b[1]; l2 += out_b[2]; l3 += out_b[3];
    float m = fmaxf(fmaxf(l0, l1), fmaxf(l2, l3));
    float e0 = __expf(l0 - m), e1 = __expf(l1 - m), e2 = __expf(l2 - m), e3 = __expf(l3 - m);
    float inv = 1.f / (e0 + e1 + e2 + e3);
    if (j == 0) out[(size_t)n * 4 + 0] = e0 * inv;
    else if (j == 1) out[(size_t)n * 4 + 1] = e1 * inv;
    else if (j == 2) out[(size_t)n * 4 + 2] = e2 * inv;
    else if (j == 3) out[(size_t)n * 4 + 3] = e3 * inv;
  }
}

extern "C" void kernel_launch(void* const* d_in, const int* in_sizes, int n_in,
                              void* d_out, int out_size, void* d_ws, size_t ws_size,
                              hipStream_t stream) {
  const float* x    = (const float*)d_in[0];
  const int*   ei   = (const int*)d_in[1];   // (2, NE): src row then dst row
  const float* attn = (const float*)d_in[2];
  const float* czw  = (const float*)d_in[3];
  const float* czb  = (const float*)d_in[4];
  // d_in[5], d_in[6]: conv_r_* -- dead (H0*R == 0)
  const float* chw  = (const float*)d_in[7];
  const float* chb  = (const float*)d_in[8];
  const float* lzw  = (const float*)d_in[9];
  const float* lzb  = (const float*)d_in[10];
  // d_in[11], d_in[12]: lin_r_* -- dead
  const float* lhw  = (const float*)d_in[13];
  const float* lhb  = (const float*)d_in[14];
  const float* outw = (const float*)d_in[15];
  const float* outb = (const float*)d_in[16];
  float* out = (float*)d_out;

  char* ws = (char*)d_ws;
  size_t off = 0;
  auto alloc = [&](size_t bytes) {
    void* p = ws + off;
    off += (bytes + 255) & ~(size_t)255;
    return p;
  };
  int*   deg         = (int*)alloc(NN * 4);
  int*   row_start   = (int*)alloc(NN * 4);
  int*   cursor      = (int*)alloc(NN * 4);
  int*   csr_src     = (int*)alloc(NE * 4);
  float* dinv        = (float*)alloc(NN * 4);
  int*   chunk_total = (int*)alloc(128 * 4);
  int*   chunk_off   = (int*)alloc(128 * 4);
  float* Az          = (float*)alloc(IN_F * 64 * 4);
  float* Ah          = (float*)alloc(IN_F * 64 * 4);
  float* cz          = (float*)alloc(64 * 4);
  float* ch          = (float*)alloc(64 * 4);
  float* probs       = (float*)alloc(PERIODS * 4);

  hipMemsetAsync(deg, 0, NN * 4, stream);
  k_prep<<<1, 1024, 0, stream>>>(attn, czw, czb, chw, chb, lzw, lzb, lhw, lhb,
                                 Az, Ah, cz, ch, probs);
  k_hist<<<(NE + 255) / 256, 256, 0, stream>>>(ei + NE, deg);
  k_scan_a<<<N_CHUNKS, SCAN_B, 0, stream>>>(deg, row_start, dinv, chunk_total);
  k_scan_b<<<1, 128, 0, stream>>>(chunk_total, chunk_off);
  k_scan_c<<<N_CHUNKS, SCAN_B, 0, stream>>>(row_start, chunk_off, cursor);
  k_fill<<<(NE + 255) / 256, 256, 0, stream>>>(ei, ei + NE, cursor, csr_src);
  k_main<<<NN, 192, 0, stream>>>(x, csr_src, row_start, deg, dinv,
                                 Az, Ah, cz, ch, probs, outw, outb, out);
}

// Round 2
// 556.297 us; speedup vs baseline: 1.5155x; 1.5155x over previous
//
#include <hip/hip_runtime.h>
#include <math.h>

#define NN 100000
#define NE 1600000
#define IN_F 16
#define OUT_F 64
#define PERIODS 12
#define FP (IN_F * PERIODS) /* 192 */
#define N_PHASE 4
#define SCAN_B 1024
#define N_CHUNKS ((NN + SCAN_B - 1) / SCAN_B) /* 98 */

__device__ __forceinline__ float bcast_lane(float v, int lane) {
  return __int_as_float(__builtin_amdgcn_readlane(__float_as_int(v), lane));
}

// ---------------- prep: fused weights + softmax(attn) ----------------
// H0 stays zero for all periods => R path dead; only top 64 rows of lin_* matter.
// Az = conv_z_w @ lin_z_w[:64], cz = conv_z_b @ lin_z_w[:64] + lin_z_b  (same for h)
__global__ void k_prep(const float* __restrict__ attn,
                       const float* __restrict__ czw, const float* __restrict__ czb,
                       const float* __restrict__ chw, const float* __restrict__ chb,
                       const float* __restrict__ lzw, const float* __restrict__ lzb,
                       const float* __restrict__ lhw, const float* __restrict__ lhb,
                       float* __restrict__ Az, float* __restrict__ Ah,
                       float* __restrict__ cz, float* __restrict__ ch,
                       float* __restrict__ probs) {
  int t = threadIdx.x;          // 1024 threads
  int f = t >> 6, j = t & 63;   // f in [0,16), j in [0,64)
  float az = 0.f, ah = 0.f;
  for (int k = 0; k < 64; ++k) {
    az += czw[f * 64 + k] * lzw[k * 64 + j];
    ah += chw[f * 64 + k] * lhw[k * 64 + j];
  }
  Az[t] = az;
  Ah[t] = ah;
  if (t < 64) {
    float vz = lzb[t], vh = lhb[t];
    for (int k = 0; k < 64; ++k) {
      vz += czb[k] * lzw[k * 64 + t];
      vh += chb[k] * lhw[k * 64 + t];
    }
    cz[t] = vz;
    ch[t] = vh;
  }
  if (t == 0) {
    float m = -1e30f;
    for (int p = 0; p < PERIODS; ++p) m = fmaxf(m, attn[p]);
    float e[PERIODS], s = 0.f;
    for (int p = 0; p < PERIODS; ++p) { e[p] = __expf(attn[p] - m); s += e[p]; }
    for (int p = 0; p < PERIODS; ++p) probs[p] = e[p] / s;
  }
}

// ---------------- degree histogram (ILP-4) ----------------
__global__ void k_hist(const int* __restrict__ dst, int* __restrict__ deg) {
  int i = blockIdx.x * blockDim.x + threadIdx.x;
  if (i < NE / 4) {
    int4 v = ((const int4*)dst)[i];
    atomicAdd(&deg[v.x], 1);
    atomicAdd(&deg[v.y], 1);
    atomicAdd(&deg[v.z], 1);
    atomicAdd(&deg[v.w], 1);
  }
}

// ---------------- scan (3-kernel) ----------------
__global__ void k_scan_a(const int* __restrict__ deg, int* __restrict__ row_excl,
                         float* __restrict__ dinv, int* __restrict__ chunk_total) {
  __shared__ int s[SCAN_B];
  int t = threadIdx.x;
  int i = blockIdx.x * SCAN_B + t;
  int v = (i < NN) ? deg[i] : 0;
  s[t] = v;
  __syncthreads();
  for (int o = 1; o < SCAN_B; o <<= 1) {
    int add = (t >= o) ? s[t - o] : 0;
    __syncthreads();
    s[t] += add;
    __syncthreads();
  }
  if (i < NN) {
    row_excl[i] = s[t] - v;
    dinv[i] = rsqrtf((float)(v + 1));  // +1 self loop
  }
  if (t == SCAN_B - 1) chunk_total[blockIdx.x] = s[t];
}

__global__ void k_scan_b(const int* __restrict__ chunk_total, int* __restrict__ chunk_off) {
  __shared__ int s[128];
  int t = threadIdx.x;
  int v = (t < N_CHUNKS) ? chunk_total[t] : 0;
  s[t] = v;
  __syncthreads();
  for (int o = 1; o < 128; o <<= 1) {
    int add = (t >= o) ? s[t - o] : 0;
    __syncthreads();
    s[t] += add;
    __syncthreads();
  }
  chunk_off[t] = s[t] - v;
}

__global__ void k_scan_c(int* __restrict__ row_excl, const int* __restrict__ chunk_off,
                         int* __restrict__ cursor) {
  int i = blockIdx.x * SCAN_B + threadIdx.x;
  if (i < NN) {
    int r = row_excl[i] + chunk_off[blockIdx.x];
    row_excl[i] = r;
    cursor[i] = r;
  }
}

// ---------------- CSR fill (ILP-4) ----------------
__global__ void k_fill(const int* __restrict__ src, const int* __restrict__ dst,
                       int* __restrict__ cursor, int* __restrict__ csr_src) {
  int i = blockIdx.x * blockDim.x + threadIdx.x;
  if (i < NE / 4) {
    int4 sv = ((const int4*)src)[i];
    int4 dv = ((const int4*)dst)[i];
    csr_src[atomicAdd(&cursor[dv.x], 1)] = sv.x;
    csr_src[atomicAdd(&cursor[dv.y], 1)] = sv.y;
    csr_src[atomicAdd(&cursor[dv.z], 1)] = sv.z;
    csr_src[atomicAdd(&cursor[dv.w], 1)] = sv.w;
  }
}

// ---------------- fused gather + collapsed-GRU compute + head ----------------
// One wave per node. Lane l holds features {l, 64+l, 128+l} of the aggregated row y.
// Compute broadcasts y via v_readlane (compile-time lane/reg selection).
__global__ __launch_bounds__(256) void k_main(
    const float* __restrict__ x, const int* __restrict__ csr_src,
    const int* __restrict__ row_start, const int* __restrict__ deg,
    const float* __restrict__ dinv,
    const float* __restrict__ Az, const float* __restrict__ Ah,
    const float* __restrict__ cz, const float* __restrict__ ch,
    const float* __restrict__ probs,
    const float* __restrict__ out_w, const float* __restrict__ out_b,
    float* __restrict__ out) {
  int wid = threadIdx.x >> 6;
  int l = threadIdx.x & 63;
  int n = blockIdx.x * 4 + wid;   // grid = 25000 exact

  // ---- Phase A: gather  acc = sum_s dinv[s]*x[s] + dn*x[n];  y = dn*acc
  float dn = dinv[n];
  const float* xr = x + (size_t)n * FP;
  float a0 = dn * xr[l];
  float a1 = dn * xr[64 + l];
  float a2 = dn * xr[128 + l];

  int base = row_start[n];
  int cnt = deg[n];
  int i = 0;
  for (; i + 4 <= cnt; i += 4) {
    int s0 = csr_src[base + i + 0];
    int s1 = csr_src[base + i + 1];
    int s2 = csr_src[base + i + 2];
    int s3 = csr_src[base + i + 3];
    float d0 = dinv[s0], d1 = dinv[s1], d2 = dinv[s2], d3 = dinv[s3];
    const float* r0 = x + (size_t)s0 * FP;
    const float* r1 = x + (size_t)s1 * FP;
    const float* r2 = x + (size_t)s2 * FP;
    const float* r3 = x + (size_t)s3 * FP;
    float v00 = r0[l], v01 = r0[64 + l], v02 = r0[128 + l];
    float v10 = r1[l], v11 = r1[64 + l], v12 = r1[128 + l];
    float v20 = r2[l], v21 = r2[64 + l], v22 = r2[128 + l];
    float v30 = r3[l], v31 = r3[64 + l], v32 = r3[128 + l];
    a0 = fmaf(d0, v00, a0); a1 = fmaf(d0, v01, a1); a2 = fmaf(d0, v02, a2);
    a0 = fmaf(d1, v10, a0); a1 = fmaf(d1, v11, a1); a2 = fmaf(d1, v12, a2);
    a0 = fmaf(d2, v20, a0); a1 = fmaf(d2, v21, a1); a2 = fmaf(d2, v22, a2);
    a0 = fmaf(d3, v30, a0); a1 = fmaf(d3, v31, a1); a2 = fmaf(d3, v32, a2);
  }
  for (; i < cnt; ++i) {
    int s = csr_src[base + i];
    float d = dinv[s];
    const float* r = x + (size_t)s * FP;
    a0 = fmaf(d, r[l], a0);
    a1 = fmaf(d, r[64 + l], a1);
    a2 = fmaf(d, r[128 + l], a2);
  }
  float y0 = dn * a0, y1 = dn * a1, y2 = dn * a2;

  // ---- Phase B: lane l owns output feature l across all 12 periods
  float Azj[IN_F], Ahj[IN_F];
#pragma unroll
  for (int f = 0; f < IN_F; ++f) { Azj[f] = Az[f * 64 + l]; Ahj[f] = Ah[f * 64 + l]; }
  float bz = cz[l], bh = ch[l];

  float Hacc = 0.f;
#pragma unroll
  for (int p = 0; p < PERIODS; ++p) {
    float z = bz, h = bh;
#pragma unroll
    for (int f = 0; f < IN_F; ++f) {
      const int idx = f * PERIODS + p;           // compile-time after unroll
      float srcv = (idx < 64) ? y0 : ((idx < 128) ? y1 : y2);
      float yv = bcast_lane(srcv, idx & 63);
      z = fmaf(yv, Azj[f], z);
      h = fmaf(yv, Ahj[f], h);
    }
    float Z = 1.f / (1.f + __expf(-z));
    float T = 1.f - 2.f / (__expf(2.f * h) + 1.f);  // tanh
    Hacc = fmaf(probs[p], (1.f - Z) * T, Hacc);
  }

  // ---- Phase C: relu, 64->4 head, softmax (wave butterfly)
  float h = fmaxf(Hacc, 0.f);
  float4 w4 = ((const float4*)out_w)[l];
  float l0 = h * w4.x, l1 = h * w4.y, l2 = h * w4.z, l3 = h * w4.w;
#pragma unroll
  for (int o = 1; o < 64; o <<= 1) {
    l0 += __shfl_xor(l0, o, 64);
    l1 += __shfl_xor(l1, o, 64);
    l2 += __shfl_xor(l2, o, 64);
    l3 += __shfl_xor(l3, o, 64);
  }
  l0 += out_b[0]; l1 += out_b[1]; l2 += out_b[2]; l3 += out_b[3];
  float m = fmaxf(fmaxf(l0, l1), fmaxf(l2, l3));
  float e0 = __expf(l0 - m), e1 = __expf(l1 - m), e2 = __expf(l2 - m), e3 = __expf(l3 - m);
  float inv = 1.f / (e0 + e1 + e2 + e3);
  if (l < 4) {
    float v = (l == 0) ? e0 * inv : (l == 1) ? e1 * inv : (l == 2) ? e2 * inv : e3 * inv;
    out[(size_t)n * 4 + l] = v;
  }
}

extern "C" void kernel_launch(void* const* d_in, const int* in_sizes, int n_in,
                              void* d_out, int out_size, void* d_ws, size_t ws_size,
                              hipStream_t stream) {
  const float* x    = (const float*)d_in[0];
  const int*   ei   = (const int*)d_in[1];   // (2, NE): src row then dst row
  const float* attn = (const float*)d_in[2];
  const float* czw  = (const float*)d_in[3];
  const float* czb  = (const float*)d_in[4];
  // d_in[5..6]: conv_r_* dead (H0*R == 0); d_in[11..12]: lin_r_* dead
  const float* chw  = (const float*)d_in[7];
  const float* chb  = (const float*)d_in[8];
  const float* lzw  = (const float*)d_in[9];
  const float* lzb  = (const float*)d_in[10];
  const float* lhw  = (const float*)d_in[13];
  const float* lhb  = (const float*)d_in[14];
  const float* outw = (const float*)d_in[15];
  const float* outb = (const float*)d_in[16];
  float* out = (float*)d_out;

  char* ws = (char*)d_ws;
  size_t off = 0;
  auto alloc = [&](size_t bytes) {
    void* p = ws + off;
    off += (bytes + 255) & ~(size_t)255;
    return p;
  };
  int*   deg         = (int*)alloc(NN * 4);
  int*   row_start   = (int*)alloc(NN * 4);
  int*   cursor      = (int*)alloc(NN * 4);
  int*   csr_src     = (int*)alloc(NE * 4);
  float* dinv        = (float*)alloc(NN * 4);
  int*   chunk_total = (int*)alloc(128 * 4);
  int*   chunk_off   = (int*)alloc(128 * 4);
  float* Az          = (float*)alloc(IN_F * 64 * 4);
  float* Ah          = (float*)alloc(IN_F * 64 * 4);
  float* cz          = (float*)alloc(64 * 4);
  float* ch          = (float*)alloc(64 * 4);
  float* probs       = (float*)alloc(PERIODS * 4);

  hipMemsetAsync(deg, 0, NN * 4, stream);
  k_prep<<<1, 1024, 0, stream>>>(attn, czw, czb, chw, chb, lzw, lzb, lhw, lhb,
                                 Az, Ah, cz, ch, probs);
  k_hist<<<(NE / 4 + 255) / 256, 256, 0, stream>>>(ei + NE, deg);
  k_scan_a<<<N_CHUNKS, SCAN_B, 0, stream>>>(deg, row_start, dinv, chunk_total);
  k_scan_b<<<1, 128, 0, stream>>>(chunk_total, chunk_off);
  k_scan_c<<<N_CHUNKS, SCAN_B, 0, stream>>>(row_start, chunk_off, cursor);
  k_fill<<<(NE / 4 + 255) / 256, 256, 0, stream>>>(ei, ei + NE, cursor, csr_src);
  k_main<<<NN / 4, 256, 0, stream>>>(x, csr_src, row_start, deg, dinv,
                                     Az, Ah, cz, ch, probs, outw, outb, out);
}